// Round 14
// baseline (284.418 us; speedup 1.0000x reference)
//
#include <hip/hip_runtime.h>
#include <hip/hip_bf16.h>

#define NN 50000
#define NE 800000
#define NEG 0.2f
#define BNEPS 1e-5f
#define NB_CVT 61
#define NB_EDGE 3125   // NE/256
#define NB1 200        // bin pass blocks
#define CH1 4000       // edges per bin block
#define NBKT 250       // dst-range buckets (200 nodes each)
#define CAPBKT 4096    // per-bucket capacity (mean 3200, >15 sd margin)
#define MAXS 288       // per-aggr-block precomputed slots (8 nodes, Poisson(128), +14sd)
#define NPARTS 32      // BN partial buffers per layer
#define NB_FRONT (NB_CVT + 1 + NB1)
#define NB_MID (NBKT + NN/16)

typedef __hip_bfloat16 bf16;
typedef unsigned short u16;
typedef unsigned int u32;
__device__ __forceinline__ float b2f(bf16 v){ return __bfloat162float(v); }
__device__ __forceinline__ float u2f(u16 u){ return __uint_as_float(((u32)u) << 16); }
__device__ __forceinline__ u16 f2u(float f){ bf16 b = __float2bfloat16(f); return *(u16*)&b; }

struct CvtArgs { const void* src[11]; int off[11]; int cnt[11]; };

// ---- fused front: dtype-detect + param convert + aet prep  |  bucket binning ----
__global__ __launch_bounds__(256) void k_front(CvtArgs a, const void* eeraw,
        const void* aeraw, const int* __restrict__ src, const int* __restrict__ dst,
        const int* __restrict__ ety,
        float* __restrict__ cw, float* __restrict__ aet, int* __restrict__ flag,
        int* __restrict__ bcur, u32* __restrict__ bins){
  int t = threadIdx.x, b = blockIdx.x;
  if (b >= NB_CVT + 1){
    // ---- binning role: LDS-counted bucket scatter, block-owned runs ----
    __shared__ int cnt[NBKT], start[NBKT], cur[NBKT];
    __shared__ int dcache[CH1];
    int bb = b - (NB_CVT + 1);
    for (int i = t; i < NBKT; i += 256){ cnt[i] = 0; cur[i] = 0; }
    __syncthreads();
    int base = bb*CH1;
    for (int k = t; k < CH1; k += 256){
      int d = dst[base + k];
      dcache[k] = d;
      atomicAdd(&cnt[(u32)d/200u], 1);
    }
    __syncthreads();
    for (int i = t; i < NBKT; i += 256) start[i] = atomicAdd(&bcur[i], cnt[i]);
    __syncthreads();
    for (int k = t; k < CH1; k += 256){
      int e = base + k;
      u32 d = (u32)dcache[k];
      u32 bk = d/200u;
      int pos = start[bk] + atomicAdd(&cur[bk], 1);
      if (pos < CAPBKT)
        bins[bk*CAPBKT + pos] = (u32)src[e] | ((u32)ety[e] << 16) | ((d - bk*200u) << 18);
    }
    return;
  }
  // ---- setup role ----
  __shared__ int sflag;
  if (t < 64){
    const u16* u = (const u16*)a.src[0];      // atom_emb raw bits
    int hit = 0;
    for (int i = t; i < 512; i += 64){
      int ex = (u[i] >> 7) & 0xFF;
      if (ex >= 0x8A || (ex != 0 && ex <= 0x60)) hit = 1;
    }
    unsigned long long bl = __ballot(hit);
    if (t == 0) sflag = (bl != 0ULL) ? 1 : 0; // 1 = f32 inputs, 0 = bf16
  }
  __syncthreads();
  int f = sflag;
  if (b == 0 && t == 0) *flag = f;
  if (b < NB_CVT){
    int i = b*256 + t;
    #pragma unroll
    for (int s = 0; s < 11; ++s){
      int j = i - a.off[s];
      if (j >= 0 && j < a.cnt[s])
        cw[a.off[s] + j] = f ? ((const float*)a.src[s])[j]
                             : b2f(((const bf16*)a.src[s])[j]);
    }
  } else if (t < 48){                         // aet[l*16 + ty*4 + h]
    int l = t >> 4, ty = (t >> 2) & 3, h = t & 3;
    float s = 0.f;
    for (int cc = 0; cc < 16; ++cc){
      int ei = l*256 + ty*64 + h*16 + cc;
      int ai = l*64 + h*16 + cc;
      float ev = f ? ((const float*)eeraw)[ei] : b2f(((const bf16*)eeraw)[ei]);
      float av = f ? ((const float*)aeraw)[ai] : b2f(((const bf16*)aeraw)[ai]);
      s += ev*av;
    }
    aet[t] = s;
  }
}

// ---- fused mid: per-bucket CSR counting sort (250) | layer-0 proj (3125) ----
__global__ __launch_bounds__(256) void k_mid(const int* __restrict__ bcur,
        const u32* __restrict__ bins,
        int* __restrict__ cpack, int* __restrict__ rowst, int* __restrict__ cnt4,
        const int* __restrict__ xidx, const float* __restrict__ aembf,
        const float* __restrict__ Wl, const float* __restrict__ att_s,
        const float* __restrict__ att_d,
        float* __restrict__ x, u16* __restrict__ bxl,
        float* __restrict__ asrc, float* __restrict__ adst){
  __shared__ __align__(16) char smem[17408];
  int t = threadIdx.x, b = blockIdx.x;
  if (b < NBKT){
    // ---- CSR role ----
    int* c4   = (int*)smem;            // 800
    int* nst  = c4 + 800;              // 200
    int* ncur = nst + 200;             // 200
    int* bco  = ncur + 200;            // 256
    int* s    = bco + 256;             // 256
    for (int i = t; i < 800; i += 256) c4[i] = 0;
    if (t < 200) ncur[t] = 0;
    int v = 0;
    if (t < NBKT){ v = bcur[t]; if (v > CAPBKT) v = CAPBKT; }
    bco[t] = v; s[t] = v;
    __syncthreads();
    for (int o = 1; o < 256; o <<= 1){
      int a2 = s[t]; int add = (t >= o) ? s[t-o] : 0;
      __syncthreads(); s[t] = a2 + add; __syncthreads();
    }
    int gb = s[b] - bco[b];
    int tot = bco[b];
    int total = s[255];
    __syncthreads();
    for (int i = t; i < tot; i += 256){
      u32 e = bins[b*CAPBKT + i];
      atomicAdd(&c4[((e >> 18) & 0xFF)*4 + ((e >> 16) & 3)], 1);
    }
    __syncthreads();
    int deg = 0;
    if (t < 200) deg = c4[t*4] + c4[t*4+1] + c4[t*4+2] + c4[t*4+3];
    s[t] = deg; __syncthreads();
    for (int o = 1; o < 256; o <<= 1){
      int a2 = s[t]; int add = (t >= o) ? s[t-o] : 0;
      __syncthreads(); s[t] = a2 + add; __syncthreads();
    }
    if (t < 200) nst[t] = s[t] - deg;
    __syncthreads();
    if (t < 200){
      int n = b*200 + t;
      rowst[n] = gb + nst[t];
      *(int4*)&cnt4[n*4] = make_int4(c4[t*4], c4[t*4+1], c4[t*4+2], c4[t*4+3]);
    }
    if (b == 0 && t == 0) rowst[NN] = total;
    for (int i = t; i < tot; i += 256){
      u32 e = bins[b*CAPBKT + i];
      int nl = (e >> 18) & 0xFF;
      int pos = nst[nl] + atomicAdd(&ncur[nl], 1);
      cpack[gb + pos] = (int)(e & 0x3FFFF);   // src | ty<<16
    }
    return;
  }
  // ---- proj0 role ----
  float* Ws = (float*)smem;            // 4096 floats
  float* xs = Ws + 4096;               // 256 floats
  int bp = b - NBKT;
  for (int i = t; i < 4096; i += 256) Ws[i] = Wl[i];
  int c = t & 63, wv = t >> 6;
  float ats = att_s[c], atd = att_d[c];
  for (int pass = 0; pass < 4; ++pass){
    int n = bp*16 + pass*4 + wv;
    float xv = aembf[xidx[n]*64 + c];
    x[n*64 + c] = xv;
    __syncthreads();
    xs[t] = xv;
    __syncthreads();
    const float* xr = &xs[wv*64];
    float acc = 0.f;
    #pragma unroll
    for (int k = 0; k < 64; ++k) acc += xr[k]*Ws[k*64 + c];
    bxl[n*64 + c] = f2u(acc);
    float vs = acc*ats, vd = acc*atd;
    #pragma unroll
    for (int o = 8; o >= 1; o >>= 1){ vs += __shfl_xor(vs,o,64); vd += __shfl_xor(vd,o,64); }
    if ((c & 15) == 0){ asrc[n*4 + (c>>4)] = vs; adst[n*4 + (c>>4)] = vd; }
  }
}

// BN(prev)+relu+residual then project; stats reduced inline from bnpart[l]
__global__ __launch_bounds__(256) void k_bnproj(
    const float* __restrict__ opre, const float* __restrict__ bnp,
    const float* __restrict__ gam, const float* __restrict__ bet,
    const float* __restrict__ Wl,
    const float* __restrict__ att_s, const float* __restrict__ att_d,
    float* __restrict__ x, u16* __restrict__ bxl,
    float* __restrict__ asrc, float* __restrict__ adst){
  __shared__ float Ws[4096];
  __shared__ float xs[256];
  __shared__ float sred[256];
  __shared__ float stat[128];
  int t = threadIdx.x;
  // inline BN stats: sum over NPARTS partials (L2-hot broadcast)
  {
    int cc = t & 127;
    float s = 0.f;
    for (int p2 = t >> 7; p2 < NPARTS; p2 += 2) s += bnp[p2*128 + cc];
    sred[t] = s;
  }
  for (int i = t; i < 4096; i += 256) Ws[i] = Wl[i];
  __syncthreads();
  if (t < 128) stat[t] = sred[t] + sred[128 + t];
  __syncthreads();
  int c = t & 63, wv = t >> 6;
  float mu  = stat[c] * (1.f/NN);
  float var = stat[64+c] * (1.f/NN) - mu*mu;
  float rstd = rsqrtf(var + BNEPS);
  float g = gam[c], be = bet[c];
  float ats = att_s[c], atd = att_d[c];
  for (int pass = 0; pass < 4; ++pass){
    int n = blockIdx.x*16 + pass*4 + wv;
    float o = (opre[n*64 + c] - mu)*rstd*g + be;
    float xv = x[n*64 + c] + fmaxf(o, 0.f);
    x[n*64 + c] = xv;
    __syncthreads();
    xs[t] = xv;
    __syncthreads();
    const float* xr = &xs[wv*64];
    float acc = 0.f;
    #pragma unroll
    for (int k = 0; k < 64; ++k) acc += xr[k]*Ws[k*64 + c];
    bxl[n*64 + c] = f2u(acc);
    float vs = acc*ats, vd = acc*atd;
    #pragma unroll
    for (int o2 = 8; o2 >= 1; o2 >>= 1){ vs += __shfl_xor(vs,o2,64); vd += __shfl_xor(vd,o2,64); }
    if ((c & 15) == 0){ asrc[n*4 + (c>>4)] = vs; adst[n*4 + (c>>4)] = vd; }
  }
}

// ---- aggregation: 8 nodes/block, channel-pair packing + hoisted type-term.
//      Phase 1: packed (src|w_bf16) per head in LDS + wsum[node][ty][h] table.
//      Phase 2: per edge = 1 LDS read + 1 gather + 2 FMA. den = wself + sum(wsum).
__global__ __launch_bounds__(256) void k_aggr(
    const u16* __restrict__ bxl,
    const float* __restrict__ asrc, const float* __restrict__ adst,
    const int* __restrict__ cnt4, const int* __restrict__ rowst,
    const int* __restrict__ cpack,
    const float* __restrict__ eeg, const float* __restrict__ aetg,
    const float* __restrict__ biasg,
    float* __restrict__ opre, float* __restrict__ bnp){
  __shared__ __align__(16) float ee[256];
  __shared__ float aetL[16];
  __shared__ float adl[32];
  __shared__ u32 wsl[4*MAXS];        // [head][slot]: src<<16 | w_bf16
  __shared__ float wsum[128];        // [node][ty][head]
  __shared__ float redA[256], redB[256];
  __shared__ int rs[9];
  int t = threadIdx.x;
  int n0 = blockIdx.x*8;
  ee[t] = eeg[t];
  if (t < 16) aetL[t] = aetg[t];
  if (t >= 32 && t < 64) adl[t-32] = adst[n0*4 + (t-32)];
  if (t >= 64 && t < 73) rs[t-64] = rowst[n0 + (t-64)];
  if (t >= 128) wsum[t-128] = 0.f;
  __syncthreads();
  int jb0 = rs[0], cnt = rs[8] - jb0;
  int lim = cnt < MAXS ? cnt : MAXS;
  // phase 1: weights -> packed LDS + per-(node,ty,head) weight sums
  for (int s = t; s < lim; s += 256){
    int j = jb0 + s;
    int pk = cpack[j];
    int sr = pk & 0xFFFF, ty = pk >> 16;
    int dl = (j>=rs[1])+(j>=rs[2])+(j>=rs[3])+(j>=rs[4])+(j>=rs[5])+(j>=rs[6])+(j>=rs[7]);
    float4 as4 = *(const float4*)&asrc[sr*4];
    float a0 = as4.x + adl[dl*4+0] + aetL[ty*4+0]; a0 = a0>=0.f ? a0 : NEG*a0;
    float a1 = as4.y + adl[dl*4+1] + aetL[ty*4+1]; a1 = a1>=0.f ? a1 : NEG*a1;
    float a2 = as4.z + adl[dl*4+2] + aetL[ty*4+2]; a2 = a2>=0.f ? a2 : NEG*a2;
    float a3 = as4.w + adl[dl*4+3] + aetL[ty*4+3]; a3 = a3>=0.f ? a3 : NEG*a3;
    u32 sr16 = (u32)sr << 16;
    u16 b0 = f2u(__expf(a0)), b1 = f2u(__expf(a1));
    u16 b2 = f2u(__expf(a2)), b3 = f2u(__expf(a3));
    wsl[s]        = sr16 | b0;
    wsl[MAXS+s]   = sr16 | b1;
    wsl[2*MAXS+s] = sr16 | b2;
    wsl[3*MAXS+s] = sr16 | b3;
    int wb = dl*16 + ty*4;
    atomicAdd(&wsum[wb+0], u2f(b0));
    atomicAdd(&wsum[wb+1], u2f(b1));
    atomicAdd(&wsum[wb+2], u2f(b2));
    atomicAdd(&wsum[wb+3], u2f(b3));
  }
  __syncthreads();
  // phase 2: wave wv handles nodes wv and wv+4; half-waves split edge pairs
  int wv = t >> 6, lane = t & 63;
  int ep = lane >> 5, li = lane & 31;
  int ci = li << 1, h = ci >> 4;
  const u32* bxl32 = (const u32*)bxl;
  const u32* whp = &wsl[h*MAXS];
  float sA0 = 0.f, sA1 = 0.f, sB0 = 0.f, sB1 = 0.f;
  #pragma unroll
  for (int half = 0; half < 2; ++half){
    int node = wv + half*4;
    int n = n0 + node;
    int jb = rs[node], je = rs[node+1];
    int4 c4 = *(const int4*)&cnt4[n*4];
    int deg = c4.x + c4.y + c4.z + c4.w;
    float inv = 1.f / (float)(deg > 0 ? deg : 1);
    float2 eA = *(const float2*)&ee[ci];
    float2 eB = *(const float2*)&ee[64+ci];
    float2 eC = *(const float2*)&ee[128+ci];
    float2 eD = *(const float2*)&ee[192+ci];
    float aes = ((float)c4.x*aetL[h] + (float)c4.y*aetL[4+h]
               + (float)c4.z*aetL[8+h] + (float)c4.w*aetL[12+h]) * inv;
    float adn = adl[node*4 + h];
    float a = asrc[n*4 + h] + adn + aes;
    a = a >= 0.f ? a : NEG*a;
    float wself = __expf(a);
    float acc0 = 0.f, acc1 = 0.f, den = 0.f;
    if (ep == 0){
      float eam0 = ((float)c4.x*eA.x + (float)c4.y*eB.x + (float)c4.z*eC.x + (float)c4.w*eD.x)*inv;
      float eam1 = ((float)c4.x*eA.y + (float)c4.y*eB.y + (float)c4.z*eC.y + (float)c4.w*eD.y)*inv;
      u32 vs_ = bxl32[n*32 + li];
      float s0 = wsum[node*16 + h],     s1w = wsum[node*16 + 4 + h];
      float s2w = wsum[node*16 + 8 + h], s3w = wsum[node*16 + 12 + h];
      den = wself + s0 + s1w + s2w + s3w;
      acc0 = wself*(__uint_as_float(vs_ << 16) + eam0)
           + s0*eA.x + s1w*eB.x + s2w*eC.x + s3w*eD.x;
      acc1 = wself*(__uint_as_float(vs_ & 0xFFFF0000u) + eam1)
           + s0*eA.y + s1w*eB.y + s2w*eC.y + s3w*eD.y;
    }
    int jlim = jb0 + lim;
    int jeP = je < jlim ? je : jlim;
    int j = jb;
    for (; j + 8 <= jeP; j += 8){
      int so = j - jb0 + ep;
      u32 p0 = whp[so],   p1 = whp[so+2], p2 = whp[so+4], p3 = whp[so+6];
      u32 v0 = bxl32[(p0>>16)*32 + li], v1 = bxl32[(p1>>16)*32 + li];
      u32 v2 = bxl32[(p2>>16)*32 + li], v3 = bxl32[(p3>>16)*32 + li];
      float w0 = __uint_as_float(p0 << 16), w1 = __uint_as_float(p1 << 16);
      float w2 = __uint_as_float(p2 << 16), w3 = __uint_as_float(p3 << 16);
      acc0 += w0*__uint_as_float(v0 << 16);
      acc1 += w0*__uint_as_float(v0 & 0xFFFF0000u);
      acc0 += w1*__uint_as_float(v1 << 16);
      acc1 += w1*__uint_as_float(v1 & 0xFFFF0000u);
      acc0 += w2*__uint_as_float(v2 << 16);
      acc1 += w2*__uint_as_float(v2 & 0xFFFF0000u);
      acc0 += w3*__uint_as_float(v3 << 16);
      acc1 += w3*__uint_as_float(v3 & 0xFFFF0000u);
    }
    for (; j + 2 <= jeP; j += 2){
      int so = j - jb0 + ep;
      u32 p = whp[so];
      u32 v = bxl32[(p>>16)*32 + li];
      float w = __uint_as_float(p << 16);
      acc0 += w*__uint_as_float(v << 16);
      acc1 += w*__uint_as_float(v & 0xFFFF0000u);
    }
    if (j < jeP && ep == 0){          // odd leftover: half-wave 0 only
      int so = j - jb0;
      u32 p = whp[so];
      u32 v = bxl32[(p>>16)*32 + li];
      float w = __uint_as_float(p << 16);
      acc0 += w*__uint_as_float(v << 16);
      acc1 += w*__uint_as_float(v & 0xFFFF0000u);
    }
    int jf = jeP > jb ? jeP : jb;     // overflow fallback (never for this data)
    for (j = jf; j < je; ++j){
      if (ep == 0){
        int pk = cpack[j];
        int s_ = pk & 0xFFFF, ty = pk >> 16;
        float aa = asrc[s_*4 + h] + adn + aetL[ty*4 + h];
        aa = aa >= 0.f ? aa : NEG*aa;
        float wj = __expf(aa);
        u32 v = bxl32[s_*32 + li];
        float2 e = *(const float2*)&ee[ty*64 + ci];
        acc0 += wj*(__uint_as_float(v << 16) + e.x);
        acc1 += wj*(__uint_as_float(v & 0xFFFF0000u) + e.y);
        den += wj;
      }
    }
    // merge half-waves (den is complete on ep==0 already)
    acc0 += __shfl_xor(acc0, 32, 64);
    acc1 += __shfl_xor(acc1, 32, 64);
    if (ep == 0){
      float2 bi = *(const float2*)&biasg[ci];
      float out0 = acc0/den + bi.x;
      float out1 = acc1/den + bi.y;
      *(float2*)&opre[n*64 + ci] = make_float2(out0, out1);
      sA0 += out0; sA1 += out1; sB0 += out0*out0; sB1 += out1*out1;
    }
  }
  if (ep == 0){
    redA[wv*64 + ci] = sA0; redA[wv*64 + ci + 1] = sA1;
    redB[wv*64 + ci] = sB0; redB[wv*64 + ci + 1] = sB1;
  }
  __syncthreads();
  int part = blockIdx.x & (NPARTS-1);
  if (t < 64){
    atomicAdd(&bnp[part*128 + t], redA[t]+redA[64+t]+redA[128+t]+redA[192+t]);
  } else if (t < 128){
    int cc = t - 64;
    atomicAdd(&bnp[part*128 + 64 + cc], redB[cc]+redB[64+cc]+redB[128+cc]+redB[192+cc]);
  }
}

// ---- prediction head: BN(layer2) inline stats + residual + per-node dots ----
__global__ __launch_bounds__(256) void k_bnpred(
    const float* __restrict__ x, const float* __restrict__ opre,
    const float* __restrict__ bnp, const float* __restrict__ gam,
    const float* __restrict__ bet, const float* __restrict__ pW,
    float* __restrict__ s1, float* __restrict__ s2){
  __shared__ float sred[256];
  __shared__ float stat[128];
  int t = threadIdx.x;
  {
    int cc = t & 127;
    float s = 0.f;
    for (int p2 = t >> 7; p2 < NPARTS; p2 += 2) s += bnp[p2*128 + cc];
    sred[t] = s;
  }
  __syncthreads();
  if (t < 128) stat[t] = sred[t] + sred[128 + t];
  __syncthreads();
  int wv = t >> 6, c = t & 63;
  int n = blockIdx.x*4 + wv;
  float mu  = stat[c] * (1.f/NN);
  float var = stat[64+c] * (1.f/NN) - mu*mu;
  float o = (opre[n*64 + c] - mu)*rsqrtf(var + BNEPS)*gam[c] + bet[c];
  float xv = x[n*64 + c] + fmaxf(o, 0.f);
  float v1 = xv*pW[c], v2 = xv*pW[64 + c];
  #pragma unroll
  for (int o2 = 32; o2 >= 1; o2 >>= 1){ v1 += __shfl_xor(v1,o2,64); v2 += __shfl_xor(v2,o2,64); }
  if (c == 0){ s1[n] = v1; s2[n] = v2; }
}

__global__ void k_pred_edge(const int* __restrict__ src, const int* __restrict__ dst,
        const float* __restrict__ s1, const float* __restrict__ s2,
        const float* __restrict__ pbf, const int* __restrict__ flag, void* out){
  int e = blockIdx.x*256 + threadIdx.x;
  if (e < NE){
    float v = s1[src[e]] + s2[dst[e]] + pbf[0];
    if (*flag) ((float*)out)[e] = v;
    else       ((bf16*)out)[e] = __float2bfloat16(v);
  }
}

// ---- launch ----
extern "C" void kernel_launch(void* const* d_in, const int* in_sizes, int n_in,
                              void* d_out, int out_size, void* d_ws, size_t ws_size,
                              hipStream_t stream){
  const int*  xidx = (const int*)d_in[0];
  const int*  eidx = (const int*)d_in[1];
  const int*  ety  = (const int*)d_in[2];
  const int* srcp = eidx, *dstp = eidx + NE;

  // 256B-aligned bump allocator
  char* base = (char*)d_ws;
  auto alloc = [&](size_t bytes) -> char* {
    char* r = base; base += (bytes + 255) & ~(size_t)255; return r;
  };
  float* x      = (float*)alloc(NN*64*4);
  float* opre   = (float*)alloc(NN*64*4);
  float* asrc   = (float*)alloc(NN*4*4);
  float* adst   = (float*)alloc(NN*4*4);
  float* s1     = (float*)alloc(NN*4);
  float* s2     = (float*)alloc(NN*4);
  float* cw     = (float*)alloc(15392*4);
  float* aet    = (float*)alloc(64*4);
  char*  zchunk = alloc(3*NPARTS*128*4 + 256*4);  // bnpart[3] + bcur
  float* bnpart = (float*)zchunk;
  int*   bcur   = (int*)(zchunk + 3*NPARTS*128*4);
  size_t zbytes = 3*NPARTS*128*4 + 256*4;
  u32*   bins   = (u32*)alloc((size_t)NBKT*CAPBKT*4);
  int*   cpack  = (int*)alloc(NE*4);
  int*   rowst  = (int*)alloc((NN+4)*4);
  int*   cnt4   = (int*)alloc(NN*4*4);
  int*   flag   = (int*)alloc(256);
  u16*   bxl    = (u16*)alloc(NN*64*2);

  const int O_AEMB = 0,     N_AEMB = 1024;
  const int O_W    = 1024,  N_W    = 12288;
  const int O_AS   = 13312, N_AS   = 192;
  const int O_AD   = 13504, N_AD   = 192;
  const int O_AE   = 13696, N_AE   = 192;
  const int O_BI   = 13888, N_BI   = 192;
  const int O_EE   = 14080, N_EE   = 768;
  const int O_GA   = 14848, N_GA   = 192;
  const int O_BE   = 15040, N_BE   = 192;
  const int O_PW   = 15232, N_PW   = 128;
  const int O_PB   = 15360, N_PB   = 1;

  CvtArgs ca;
  ca.src[0]=d_in[3];  ca.off[0]=O_AEMB; ca.cnt[0]=N_AEMB;
  ca.src[1]=d_in[4];  ca.off[1]=O_W;    ca.cnt[1]=N_W;
  ca.src[2]=d_in[5];  ca.off[2]=O_AS;   ca.cnt[2]=N_AS;
  ca.src[3]=d_in[6];  ca.off[3]=O_AD;   ca.cnt[3]=N_AD;
  ca.src[4]=d_in[7];  ca.off[4]=O_AE;   ca.cnt[4]=N_AE;
  ca.src[5]=d_in[8];  ca.off[5]=O_BI;   ca.cnt[5]=N_BI;
  ca.src[6]=d_in[9];  ca.off[6]=O_EE;   ca.cnt[6]=N_EE;
  ca.src[7]=d_in[10]; ca.off[7]=O_GA;   ca.cnt[7]=N_GA;
  ca.src[8]=d_in[11]; ca.off[8]=O_BE;   ca.cnt[8]=N_BE;
  ca.src[9]=d_in[12]; ca.off[9]=O_PW;   ca.cnt[9]=N_PW;
  ca.src[10]=d_in[13];ca.off[10]=O_PB;  ca.cnt[10]=N_PB;

  hipMemsetAsync(zchunk, 0, zbytes, stream);
  k_front<<<NB_FRONT, 256, 0, stream>>>(ca, d_in[9], d_in[7], srcp, dstp, ety,
                                        cw, aet, flag, bcur, bins);
  k_mid<<<NB_MID, 256, 0, stream>>>(bcur, bins, cpack, rowst, cnt4,
                                    xidx, cw + O_AEMB, cw + O_W,
                                    cw + O_AS, cw + O_AD, x, bxl, asrc, adst);
  for (int l = 0; l < 3; ++l){
    k_aggr<<<NN/8, 256, 0, stream>>>(bxl, asrc, adst, cnt4, rowst, cpack,
                                     cw + O_EE + l*256, aet + l*16,
                                     cw + O_BI + l*64, opre, bnpart + l*NPARTS*128);
    if (l < 2)
      k_bnproj<<<NN/16, 256, 0, stream>>>(opre, bnpart + l*NPARTS*128,
                                          cw + O_GA + l*64, cw + O_BE + l*64,
                                          cw + O_W + (l+1)*4096,
                                          cw + O_AS + (l+1)*64, cw + O_AD + (l+1)*64,
                                          x, bxl, asrc, adst);
  }
  k_bnpred<<<NN/4, 256, 0, stream>>>(x, opre, bnpart + 2*NPARTS*128,
                                     cw + O_GA + 128, cw + O_BE + 128,
                                     cw + O_PW, s1, s2);
  k_pred_edge<<<NB_EDGE, 256, 0, stream>>>(srcp, dstp, s1, s2, cw + O_PB, flag, d_out);
}

// Round 15
// 281.895 us; speedup vs baseline: 1.0090x; 1.0090x over previous
//
#include <hip/hip_runtime.h>
#include <hip/hip_bf16.h>

#define NN 50000
#define NE 800000
#define NEG 0.2f
#define BNEPS 1e-5f
#define NB_CVT 61
#define NB_EDGE 3125   // NE/256
#define NB1 200        // bin pass blocks
#define CH1 4000       // edges per bin block
#define NBKT 250       // dst-range buckets (200 nodes each)
#define CAPBKT 4096    // per-bucket capacity (mean 3200, >15 sd margin)
#define MAXS 288       // per-aggr-block precomputed slots (8 nodes, Poisson(128), +14sd)
#define NPARTS 32      // BN partial buffers per layer
#define NB_FRONT (NB_CVT + 1 + NB1)
#define NB_MID (NBKT + NN/16)

typedef __hip_bfloat16 bf16;
typedef unsigned short u16;
typedef unsigned int u32;
__device__ __forceinline__ float b2f(bf16 v){ return __bfloat162float(v); }
__device__ __forceinline__ float u2f(u16 u){ return __uint_as_float(((u32)u) << 16); }
__device__ __forceinline__ u16 f2u(float f){ bf16 b = __float2bfloat16(f); return *(u16*)&b; }

struct CvtArgs { const void* src[11]; int off[11]; int cnt[11]; };

// ---- fused front: dtype-detect + param convert + aet prep  |  bucket binning ----
__global__ __launch_bounds__(256) void k_front(CvtArgs a, const void* eeraw,
        const void* aeraw, const int* __restrict__ src, const int* __restrict__ dst,
        const int* __restrict__ ety,
        float* __restrict__ cw, float* __restrict__ aet, int* __restrict__ flag,
        int* __restrict__ bcur, u32* __restrict__ bins){
  int t = threadIdx.x, b = blockIdx.x;
  if (b >= NB_CVT + 1){
    // ---- binning role: LDS-counted bucket scatter, block-owned runs ----
    __shared__ int cnt[NBKT], start[NBKT], cur[NBKT];
    __shared__ int dcache[CH1];
    int bb = b - (NB_CVT + 1);
    for (int i = t; i < NBKT; i += 256){ cnt[i] = 0; cur[i] = 0; }
    __syncthreads();
    int base = bb*CH1;
    for (int k = t; k < CH1; k += 256){
      int d = dst[base + k];
      dcache[k] = d;
      atomicAdd(&cnt[(u32)d/200u], 1);
    }
    __syncthreads();
    for (int i = t; i < NBKT; i += 256) start[i] = atomicAdd(&bcur[i], cnt[i]);
    __syncthreads();
    for (int k = t; k < CH1; k += 256){
      int e = base + k;
      u32 d = (u32)dcache[k];
      u32 bk = d/200u;
      int pos = start[bk] + atomicAdd(&cur[bk], 1);
      if (pos < CAPBKT)
        bins[bk*CAPBKT + pos] = (u32)src[e] | ((u32)ety[e] << 16) | ((d - bk*200u) << 18);
    }
    return;
  }
  // ---- setup role ----
  __shared__ int sflag;
  if (t < 64){
    const u16* u = (const u16*)a.src[0];      // atom_emb raw bits
    int hit = 0;
    for (int i = t; i < 512; i += 64){
      int ex = (u[i] >> 7) & 0xFF;
      if (ex >= 0x8A || (ex != 0 && ex <= 0x60)) hit = 1;
    }
    unsigned long long bl = __ballot(hit);
    if (t == 0) sflag = (bl != 0ULL) ? 1 : 0; // 1 = f32 inputs, 0 = bf16
  }
  __syncthreads();
  int f = sflag;
  if (b == 0 && t == 0) *flag = f;
  if (b < NB_CVT){
    int i = b*256 + t;
    #pragma unroll
    for (int s = 0; s < 11; ++s){
      int j = i - a.off[s];
      if (j >= 0 && j < a.cnt[s])
        cw[a.off[s] + j] = f ? ((const float*)a.src[s])[j]
                             : b2f(((const bf16*)a.src[s])[j]);
    }
  } else if (t < 48){                         // aet[l*16 + ty*4 + h]
    int l = t >> 4, ty = (t >> 2) & 3, h = t & 3;
    float s = 0.f;
    for (int cc = 0; cc < 16; ++cc){
      int ei = l*256 + ty*64 + h*16 + cc;
      int ai = l*64 + h*16 + cc;
      float ev = f ? ((const float*)eeraw)[ei] : b2f(((const bf16*)eeraw)[ei]);
      float av = f ? ((const float*)aeraw)[ai] : b2f(((const bf16*)aeraw)[ai]);
      s += ev*av;
    }
    aet[t] = s;
  }
}

// ---- fused mid: per-bucket CSR counting sort (250) | layer-0 proj (3125) ----
__global__ __launch_bounds__(256) void k_mid(const int* __restrict__ bcur,
        const u32* __restrict__ bins,
        int* __restrict__ cpack, int* __restrict__ rowst, int* __restrict__ cnt4,
        const int* __restrict__ xidx, const float* __restrict__ aembf,
        const float* __restrict__ Wl, const float* __restrict__ att_s,
        const float* __restrict__ att_d,
        float* __restrict__ x, u16* __restrict__ bxl,
        float* __restrict__ asrc, float* __restrict__ adst){
  __shared__ __align__(16) char smem[17408];
  int t = threadIdx.x, b = blockIdx.x;
  if (b < NBKT){
    // ---- CSR role ----
    int* c4   = (int*)smem;            // 800
    int* nst  = c4 + 800;              // 200
    int* ncur = nst + 200;             // 200
    int* bco  = ncur + 200;            // 256
    int* s    = bco + 256;             // 256
    for (int i = t; i < 800; i += 256) c4[i] = 0;
    if (t < 200) ncur[t] = 0;
    int v = 0;
    if (t < NBKT){ v = bcur[t]; if (v > CAPBKT) v = CAPBKT; }
    bco[t] = v; s[t] = v;
    __syncthreads();
    for (int o = 1; o < 256; o <<= 1){
      int a2 = s[t]; int add = (t >= o) ? s[t-o] : 0;
      __syncthreads(); s[t] = a2 + add; __syncthreads();
    }
    int gb = s[b] - bco[b];
    int tot = bco[b];
    int total = s[255];
    __syncthreads();
    for (int i = t; i < tot; i += 256){
      u32 e = bins[b*CAPBKT + i];
      atomicAdd(&c4[((e >> 18) & 0xFF)*4 + ((e >> 16) & 3)], 1);
    }
    __syncthreads();
    int deg = 0;
    if (t < 200) deg = c4[t*4] + c4[t*4+1] + c4[t*4+2] + c4[t*4+3];
    s[t] = deg; __syncthreads();
    for (int o = 1; o < 256; o <<= 1){
      int a2 = s[t]; int add = (t >= o) ? s[t-o] : 0;
      __syncthreads(); s[t] = a2 + add; __syncthreads();
    }
    if (t < 200) nst[t] = s[t] - deg;
    __syncthreads();
    if (t < 200){
      int n = b*200 + t;
      rowst[n] = gb + nst[t];
      *(int4*)&cnt4[n*4] = make_int4(c4[t*4], c4[t*4+1], c4[t*4+2], c4[t*4+3]);
    }
    if (b == 0 && t == 0) rowst[NN] = total;
    for (int i = t; i < tot; i += 256){
      u32 e = bins[b*CAPBKT + i];
      int nl = (e >> 18) & 0xFF;
      int pos = nst[nl] + atomicAdd(&ncur[nl], 1);
      cpack[gb + pos] = (int)(e & 0x3FFFF);   // src | ty<<16
    }
    return;
  }
  // ---- proj0 role ----
  float* Ws = (float*)smem;            // 4096 floats
  float* xs = Ws + 4096;               // 256 floats
  int bp = b - NBKT;
  for (int i = t; i < 4096; i += 256) Ws[i] = Wl[i];
  int c = t & 63, wv = t >> 6;
  float ats = att_s[c], atd = att_d[c];
  for (int pass = 0; pass < 4; ++pass){
    int n = bp*16 + pass*4 + wv;
    float xv = aembf[xidx[n]*64 + c];
    x[n*64 + c] = xv;
    __syncthreads();
    xs[t] = xv;
    __syncthreads();
    const float* xr = &xs[wv*64];
    float acc = 0.f;
    #pragma unroll
    for (int k = 0; k < 64; ++k) acc += xr[k]*Ws[k*64 + c];
    bxl[n*64 + c] = f2u(acc);
    float vs = acc*ats, vd = acc*atd;
    #pragma unroll
    for (int o = 8; o >= 1; o >>= 1){ vs += __shfl_xor(vs,o,64); vd += __shfl_xor(vd,o,64); }
    if ((c & 15) == 0){ asrc[n*4 + (c>>4)] = vs; adst[n*4 + (c>>4)] = vd; }
  }
}

// BN(prev)+relu+residual then project; stats reduced inline from bnpart[l]
__global__ __launch_bounds__(256) void k_bnproj(
    const float* __restrict__ opre, const float* __restrict__ bnp,
    const float* __restrict__ gam, const float* __restrict__ bet,
    const float* __restrict__ Wl,
    const float* __restrict__ att_s, const float* __restrict__ att_d,
    float* __restrict__ x, u16* __restrict__ bxl,
    float* __restrict__ asrc, float* __restrict__ adst){
  __shared__ float Ws[4096];
  __shared__ float xs[256];
  __shared__ float sred[256];
  __shared__ float stat[128];
  int t = threadIdx.x;
  // inline BN stats: sum over NPARTS partials (L2-hot broadcast)
  {
    int cc = t & 127;
    float s = 0.f;
    for (int p2 = t >> 7; p2 < NPARTS; p2 += 2) s += bnp[p2*128 + cc];
    sred[t] = s;
  }
  for (int i = t; i < 4096; i += 256) Ws[i] = Wl[i];
  __syncthreads();
  if (t < 128) stat[t] = sred[t] + sred[128 + t];
  __syncthreads();
  int c = t & 63, wv = t >> 6;
  float mu  = stat[c] * (1.f/NN);
  float var = stat[64+c] * (1.f/NN) - mu*mu;
  float rstd = rsqrtf(var + BNEPS);
  float g = gam[c], be = bet[c];
  float ats = att_s[c], atd = att_d[c];
  for (int pass = 0; pass < 4; ++pass){
    int n = blockIdx.x*16 + pass*4 + wv;
    float o = (opre[n*64 + c] - mu)*rstd*g + be;
    float xv = x[n*64 + c] + fmaxf(o, 0.f);
    x[n*64 + c] = xv;
    __syncthreads();
    xs[t] = xv;
    __syncthreads();
    const float* xr = &xs[wv*64];
    float acc = 0.f;
    #pragma unroll
    for (int k = 0; k < 64; ++k) acc += xr[k]*Ws[k*64 + c];
    bxl[n*64 + c] = f2u(acc);
    float vs = acc*ats, vd = acc*atd;
    #pragma unroll
    for (int o2 = 8; o2 >= 1; o2 >>= 1){ vs += __shfl_xor(vs,o2,64); vd += __shfl_xor(vd,o2,64); }
    if ((c & 15) == 0){ asrc[n*4 + (c>>4)] = vs; adst[n*4 + (c>>4)] = vd; }
  }
}

// ---- aggregation: 8 nodes/block, channel-pair packing + hoisted type-term.
//      wsl layout [slot*4 + head] (interleaved, bank-conflict-free, r10-proven).
__global__ __launch_bounds__(256) void k_aggr(
    const u16* __restrict__ bxl,
    const float* __restrict__ asrc, const float* __restrict__ adst,
    const int* __restrict__ cnt4, const int* __restrict__ rowst,
    const int* __restrict__ cpack,
    const float* __restrict__ eeg, const float* __restrict__ aetg,
    const float* __restrict__ biasg,
    float* __restrict__ opre, float* __restrict__ bnp){
  __shared__ __align__(16) float ee[256];
  __shared__ float aetL[16];
  __shared__ float adl[32];
  __shared__ __align__(16) u32 wsl[4*MAXS];  // [slot][head]: src<<16 | w_bf16
  __shared__ float wsum[128];                // [node][ty][head]
  __shared__ float redA[256], redB[256];
  __shared__ int rs[9];
  int t = threadIdx.x;
  int n0 = blockIdx.x*8;
  ee[t] = eeg[t];
  if (t < 16) aetL[t] = aetg[t];
  if (t >= 32 && t < 64) adl[t-32] = adst[n0*4 + (t-32)];
  if (t >= 64 && t < 73) rs[t-64] = rowst[n0 + (t-64)];
  if (t >= 128) wsum[t-128] = 0.f;
  __syncthreads();
  int jb0 = rs[0], cnt = rs[8] - jb0;
  int lim = cnt < MAXS ? cnt : MAXS;
  // phase 1: weights -> packed LDS (interleaved) + per-(node,ty,head) sums
  for (int s = t; s < lim; s += 256){
    int j = jb0 + s;
    int pk = cpack[j];
    int sr = pk & 0xFFFF, ty = pk >> 16;
    int dl = (j>=rs[1])+(j>=rs[2])+(j>=rs[3])+(j>=rs[4])+(j>=rs[5])+(j>=rs[6])+(j>=rs[7]);
    float4 as4 = *(const float4*)&asrc[sr*4];
    float a0 = as4.x + adl[dl*4+0] + aetL[ty*4+0]; a0 = a0>=0.f ? a0 : NEG*a0;
    float a1 = as4.y + adl[dl*4+1] + aetL[ty*4+1]; a1 = a1>=0.f ? a1 : NEG*a1;
    float a2 = as4.z + adl[dl*4+2] + aetL[ty*4+2]; a2 = a2>=0.f ? a2 : NEG*a2;
    float a3 = as4.w + adl[dl*4+3] + aetL[ty*4+3]; a3 = a3>=0.f ? a3 : NEG*a3;
    u32 sr16 = (u32)sr << 16;
    u16 b0 = f2u(__expf(a0)), b1 = f2u(__expf(a1));
    u16 b2 = f2u(__expf(a2)), b3 = f2u(__expf(a3));
    uint4 w4;
    w4.x = sr16 | b0; w4.y = sr16 | b1; w4.z = sr16 | b2; w4.w = sr16 | b3;
    *(uint4*)&wsl[s*4] = w4;
    int wb = dl*16 + ty*4;
    atomicAdd(&wsum[wb+0], u2f(b0));
    atomicAdd(&wsum[wb+1], u2f(b1));
    atomicAdd(&wsum[wb+2], u2f(b2));
    atomicAdd(&wsum[wb+3], u2f(b3));
  }
  __syncthreads();
  // phase 2: wave wv handles nodes wv and wv+4; half-waves split edge pairs
  int wv = t >> 6, lane = t & 63;
  int ep = lane >> 5, li = lane & 31;
  int ci = li << 1, h = ci >> 4;
  const u32* bxl32 = (const u32*)bxl;
  float sA0 = 0.f, sA1 = 0.f, sB0 = 0.f, sB1 = 0.f;
  #pragma unroll
  for (int half = 0; half < 2; ++half){
    int node = wv + half*4;
    int n = n0 + node;
    int jb = rs[node], je = rs[node+1];
    int4 c4 = *(const int4*)&cnt4[n*4];
    int deg = c4.x + c4.y + c4.z + c4.w;
    float inv = 1.f / (float)(deg > 0 ? deg : 1);
    float2 eA = *(const float2*)&ee[ci];
    float2 eB = *(const float2*)&ee[64+ci];
    float2 eC = *(const float2*)&ee[128+ci];
    float2 eD = *(const float2*)&ee[192+ci];
    float aes = ((float)c4.x*aetL[h] + (float)c4.y*aetL[4+h]
               + (float)c4.z*aetL[8+h] + (float)c4.w*aetL[12+h]) * inv;
    float adn = adl[node*4 + h];
    float a = asrc[n*4 + h] + adn + aes;
    a = a >= 0.f ? a : NEG*a;
    float wself = __expf(a);
    float acc0 = 0.f, acc1 = 0.f, den = 0.f;
    if (ep == 0){
      float eam0 = ((float)c4.x*eA.x + (float)c4.y*eB.x + (float)c4.z*eC.x + (float)c4.w*eD.x)*inv;
      float eam1 = ((float)c4.x*eA.y + (float)c4.y*eB.y + (float)c4.z*eC.y + (float)c4.w*eD.y)*inv;
      u32 vs_ = bxl32[n*32 + li];
      float s0 = wsum[node*16 + h],     s1w = wsum[node*16 + 4 + h];
      float s2w = wsum[node*16 + 8 + h], s3w = wsum[node*16 + 12 + h];
      den = wself + s0 + s1w + s2w + s3w;
      acc0 = wself*(__uint_as_float(vs_ << 16) + eam0)
           + s0*eA.x + s1w*eB.x + s2w*eC.x + s3w*eD.x;
      acc1 = wself*(__uint_as_float(vs_ & 0xFFFF0000u) + eam1)
           + s0*eA.y + s1w*eB.y + s2w*eC.y + s3w*eD.y;
    }
    int jlim = jb0 + lim;
    int jeP = je < jlim ? je : jlim;
    int j = jb;
    for (; j + 8 <= jeP; j += 8){
      int so = j - jb0 + ep;
      u32 p0 = wsl[(so  )*4 + h], p1 = wsl[(so+2)*4 + h];
      u32 p2 = wsl[(so+4)*4 + h], p3 = wsl[(so+6)*4 + h];
      u32 v0 = bxl32[(p0>>16)*32 + li], v1 = bxl32[(p1>>16)*32 + li];
      u32 v2 = bxl32[(p2>>16)*32 + li], v3 = bxl32[(p3>>16)*32 + li];
      float w0 = __uint_as_float(p0 << 16), w1 = __uint_as_float(p1 << 16);
      float w2 = __uint_as_float(p2 << 16), w3 = __uint_as_float(p3 << 16);
      acc0 += w0*__uint_as_float(v0 << 16);
      acc1 += w0*__uint_as_float(v0 & 0xFFFF0000u);
      acc0 += w1*__uint_as_float(v1 << 16);
      acc1 += w1*__uint_as_float(v1 & 0xFFFF0000u);
      acc0 += w2*__uint_as_float(v2 << 16);
      acc1 += w2*__uint_as_float(v2 & 0xFFFF0000u);
      acc0 += w3*__uint_as_float(v3 << 16);
      acc1 += w3*__uint_as_float(v3 & 0xFFFF0000u);
    }
    for (; j + 2 <= jeP; j += 2){
      int so = j - jb0 + ep;
      u32 p = wsl[so*4 + h];
      u32 v = bxl32[(p>>16)*32 + li];
      float w = __uint_as_float(p << 16);
      acc0 += w*__uint_as_float(v << 16);
      acc1 += w*__uint_as_float(v & 0xFFFF0000u);
    }
    if (j < jeP && ep == 0){          // odd leftover: half-wave 0 only
      int so = j - jb0;
      u32 p = wsl[so*4 + h];
      u32 v = bxl32[(p>>16)*32 + li];
      float w = __uint_as_float(p << 16);
      acc0 += w*__uint_as_float(v << 16);
      acc1 += w*__uint_as_float(v & 0xFFFF0000u);
    }
    int jf = jeP > jb ? jeP : jb;     // overflow fallback (never for this data)
    for (j = jf; j < je; ++j){
      if (ep == 0){
        int pk = cpack[j];
        int s_ = pk & 0xFFFF, ty = pk >> 16;
        float aa = asrc[s_*4 + h] + adn + aetL[ty*4 + h];
        aa = aa >= 0.f ? aa : NEG*aa;
        float wj = __expf(aa);
        u32 v = bxl32[s_*32 + li];
        float2 e = *(const float2*)&ee[ty*64 + ci];
        acc0 += wj*(__uint_as_float(v << 16) + e.x);
        acc1 += wj*(__uint_as_float(v & 0xFFFF0000u) + e.y);
        den += wj;
      }
    }
    // merge half-waves (den is complete on ep==0 already)
    acc0 += __shfl_xor(acc0, 32, 64);
    acc1 += __shfl_xor(acc1, 32, 64);
    if (ep == 0){
      float2 bi = *(const float2*)&biasg[ci];
      float out0 = acc0/den + bi.x;
      float out1 = acc1/den + bi.y;
      *(float2*)&opre[n*64 + ci] = make_float2(out0, out1);
      sA0 += out0; sA1 += out1; sB0 += out0*out0; sB1 += out1*out1;
    }
  }
  if (ep == 0){
    redA[wv*64 + ci] = sA0; redA[wv*64 + ci + 1] = sA1;
    redB[wv*64 + ci] = sB0; redB[wv*64 + ci + 1] = sB1;
  }
  __syncthreads();
  int part = blockIdx.x & (NPARTS-1);
  if (t < 64){
    atomicAdd(&bnp[part*128 + t], redA[t]+redA[64+t]+redA[128+t]+redA[192+t]);
  } else if (t < 128){
    int cc = t - 64;
    atomicAdd(&bnp[part*128 + 64 + cc], redB[cc]+redB[64+cc]+redB[128+cc]+redB[192+cc]);
  }
}

// ---- prediction head: BN(layer2) inline stats + residual + per-node dots ----
__global__ __launch_bounds__(256) void k_bnpred(
    const float* __restrict__ x, const float* __restrict__ opre,
    const float* __restrict__ bnp, const float* __restrict__ gam,
    const float* __restrict__ bet, const float* __restrict__ pW,
    float* __restrict__ s1, float* __restrict__ s2){
  __shared__ float sred[256];
  __shared__ float stat[128];
  int t = threadIdx.x;
  {
    int cc = t & 127;
    float s = 0.f;
    for (int p2 = t >> 7; p2 < NPARTS; p2 += 2) s += bnp[p2*128 + cc];
    sred[t] = s;
  }
  __syncthreads();
  if (t < 128) stat[t] = sred[t] + sred[128 + t];
  __syncthreads();
  int wv = t >> 6, c = t & 63;
  int n = blockIdx.x*4 + wv;
  float mu  = stat[c] * (1.f/NN);
  float var = stat[64+c] * (1.f/NN) - mu*mu;
  float o = (opre[n*64 + c] - mu)*rsqrtf(var + BNEPS)*gam[c] + bet[c];
  float xv = x[n*64 + c] + fmaxf(o, 0.f);
  float v1 = xv*pW[c], v2 = xv*pW[64 + c];
  #pragma unroll
  for (int o2 = 32; o2 >= 1; o2 >>= 1){ v1 += __shfl_xor(v1,o2,64); v2 += __shfl_xor(v2,o2,64); }
  if (c == 0){ s1[n] = v1; s2[n] = v2; }
}

__global__ void k_pred_edge(const int* __restrict__ src, const int* __restrict__ dst,
        const float* __restrict__ s1, const float* __restrict__ s2,
        const float* __restrict__ pbf, const int* __restrict__ flag, void* out){
  int e = blockIdx.x*256 + threadIdx.x;
  if (e < NE){
    float v = s1[src[e]] + s2[dst[e]] + pbf[0];
    if (*flag) ((float*)out)[e] = v;
    else       ((bf16*)out)[e] = __float2bfloat16(v);
  }
}

// ---- launch ----
extern "C" void kernel_launch(void* const* d_in, const int* in_sizes, int n_in,
                              void* d_out, int out_size, void* d_ws, size_t ws_size,
                              hipStream_t stream){
  const int*  xidx = (const int*)d_in[0];
  const int*  eidx = (const int*)d_in[1];
  const int*  ety  = (const int*)d_in[2];
  const int* srcp = eidx, *dstp = eidx + NE;

  // 256B-aligned bump allocator
  char* base = (char*)d_ws;
  auto alloc = [&](size_t bytes) -> char* {
    char* r = base; base += (bytes + 255) & ~(size_t)255; return r;
  };
  float* x      = (float*)alloc(NN*64*4);
  float* opre   = (float*)alloc(NN*64*4);
  float* asrc   = (float*)alloc(NN*4*4);
  float* adst   = (float*)alloc(NN*4*4);
  float* s1     = (float*)alloc(NN*4);
  float* s2     = (float*)alloc(NN*4);
  float* cw     = (float*)alloc(15392*4);
  float* aet    = (float*)alloc(64*4);
  char*  zchunk = alloc(3*NPARTS*128*4 + 256*4);  // bnpart[3] + bcur
  float* bnpart = (float*)zchunk;
  int*   bcur   = (int*)(zchunk + 3*NPARTS*128*4);
  size_t zbytes = 3*NPARTS*128*4 + 256*4;
  u32*   bins   = (u32*)alloc((size_t)NBKT*CAPBKT*4);
  int*   cpack  = (int*)alloc(NE*4);
  int*   rowst  = (int*)alloc((NN+4)*4);
  int*   cnt4   = (int*)alloc(NN*4*4);
  int*   flag   = (int*)alloc(256);
  u16*   bxl    = (u16*)alloc(NN*64*2);

  const int O_AEMB = 0,     N_AEMB = 1024;
  const int O_W    = 1024,  N_W    = 12288;
  const int O_AS   = 13312, N_AS   = 192;
  const int O_AD   = 13504, N_AD   = 192;
  const int O_AE   = 13696, N_AE   = 192;
  const int O_BI   = 13888, N_BI   = 192;
  const int O_EE   = 14080, N_EE   = 768;
  const int O_GA   = 14848, N_GA   = 192;
  const int O_BE   = 15040, N_BE   = 192;
  const int O_PW   = 15232, N_PW   = 128;
  const int O_PB   = 15360, N_PB   = 1;

  CvtArgs ca;
  ca.src[0]=d_in[3];  ca.off[0]=O_AEMB; ca.cnt[0]=N_AEMB;
  ca.src[1]=d_in[4];  ca.off[1]=O_W;    ca.cnt[1]=N_W;
  ca.src[2]=d_in[5];  ca.off[2]=O_AS;   ca.cnt[2]=N_AS;
  ca.src[3]=d_in[6];  ca.off[3]=O_AD;   ca.cnt[3]=N_AD;
  ca.src[4]=d_in[7];  ca.off[4]=O_AE;   ca.cnt[4]=N_AE;
  ca.src[5]=d_in[8];  ca.off[5]=O_BI;   ca.cnt[5]=N_BI;
  ca.src[6]=d_in[9];  ca.off[6]=O_EE;   ca.cnt[6]=N_EE;
  ca.src[7]=d_in[10]; ca.off[7]=O_GA;   ca.cnt[7]=N_GA;
  ca.src[8]=d_in[11]; ca.off[8]=O_BE;   ca.cnt[8]=N_BE;
  ca.src[9]=d_in[12]; ca.off[9]=O_PW;   ca.cnt[9]=N_PW;
  ca.src[10]=d_in[13];ca.off[10]=O_PB;  ca.cnt[10]=N_PB;

  hipMemsetAsync(zchunk, 0, zbytes, stream);
  k_front<<<NB_FRONT, 256, 0, stream>>>(ca, d_in[9], d_in[7], srcp, dstp, ety,
                                        cw, aet, flag, bcur, bins);
  k_mid<<<NB_MID, 256, 0, stream>>>(bcur, bins, cpack, rowst, cnt4,
                                    xidx, cw + O_AEMB, cw + O_W,
                                    cw + O_AS, cw + O_AD, x, bxl, asrc, adst);
  for (int l = 0; l < 3; ++l){
    k_aggr<<<NN/8, 256, 0, stream>>>(bxl, asrc, adst, cnt4, rowst, cpack,
                                     cw + O_EE + l*256, aet + l*16,
                                     cw + O_BI + l*64, opre, bnpart + l*NPARTS*128);
    if (l < 2)
      k_bnproj<<<NN/16, 256, 0, stream>>>(opre, bnpart + l*NPARTS*128,
                                          cw + O_GA + l*64, cw + O_BE + l*64,
                                          cw + O_W + (l+1)*4096,
                                          cw + O_AS + (l+1)*64, cw + O_AD + (l+1)*64,
                                          x, bxl, asrc, adst);
  }
  k_bnpred<<<NN/4, 256, 0, stream>>>(x, opre, bnpart + 2*NPARTS*128,
                                     cw + O_GA + 128, cw + O_BE + 128,
                                     cw + O_PW, s1, s2);
  k_pred_edge<<<NB_EDGE, 256, 0, stream>>>(srcp, dstp, s1, s2, cw + O_PB, flag, d_out);
}

// Round 16
// 248.170 us; speedup vs baseline: 1.1461x; 1.1359x over previous
//
#include <hip/hip_runtime.h>
#include <hip/hip_bf16.h>

#define NN 50000
#define NE 800000
#define NEG 0.2f
#define BNEPS 1e-5f
#define NB_CVT 61
#define NB_EDGE 3125   // NE/256
#define NB1 200        // bin pass blocks
#define CH1 4000       // edges per bin block
#define NBKT 250       // dst-range buckets (200 nodes each)
#define CAPBKT 4096    // per-bucket capacity (mean 3200, >15 sd margin)
#define MAXS 288       // per-aggr-block precomputed slots (8 nodes, Poisson(128), +14sd)
#define NPARTS 32      // BN partial buffers per layer
#define NB_FRONT (NB_CVT + 1 + NB1)
#define NB_MID (NBKT + NN/16)

typedef __hip_bfloat16 bf16;
typedef unsigned short u16;
typedef unsigned int u32;
__device__ __forceinline__ float b2f(bf16 v){ return __bfloat162float(v); }
__device__ __forceinline__ float u2f(u16 u){ return __uint_as_float(((u32)u) << 16); }
__device__ __forceinline__ u16 f2u(float f){ bf16 b = __float2bfloat16(f); return *(u16*)&b; }

struct CvtArgs { const void* src[11]; int off[11]; int cnt[11]; };

// ---- fused front: dtype-detect + param convert + aet prep  |  bucket binning ----
__global__ __launch_bounds__(256) void k_front(CvtArgs a, const void* eeraw,
        const void* aeraw, const int* __restrict__ src, const int* __restrict__ dst,
        const int* __restrict__ ety,
        float* __restrict__ cw, float* __restrict__ aet, int* __restrict__ flag,
        int* __restrict__ bcur, u32* __restrict__ bins){
  int t = threadIdx.x, b = blockIdx.x;
  if (b >= NB_CVT + 1){
    // ---- binning role: LDS-counted bucket scatter, block-owned runs ----
    __shared__ int cnt[NBKT], start[NBKT], cur[NBKT];
    __shared__ int dcache[CH1];
    int bb = b - (NB_CVT + 1);
    for (int i = t; i < NBKT; i += 256){ cnt[i] = 0; cur[i] = 0; }
    __syncthreads();
    int base = bb*CH1;
    for (int k = t; k < CH1; k += 256){
      int d = dst[base + k];
      dcache[k] = d;
      atomicAdd(&cnt[(u32)d/200u], 1);
    }
    __syncthreads();
    for (int i = t; i < NBKT; i += 256) start[i] = atomicAdd(&bcur[i], cnt[i]);
    __syncthreads();
    for (int k = t; k < CH1; k += 256){
      int e = base + k;
      u32 d = (u32)dcache[k];
      u32 bk = d/200u;
      int pos = start[bk] + atomicAdd(&cur[bk], 1);
      if (pos < CAPBKT)
        bins[bk*CAPBKT + pos] = (u32)src[e] | ((u32)ety[e] << 16) | ((d - bk*200u) << 18);
    }
    return;
  }
  // ---- setup role ----
  __shared__ int sflag;
  if (t < 64){
    const u16* u = (const u16*)a.src[0];      // atom_emb raw bits
    int hit = 0;
    for (int i = t; i < 512; i += 64){
      int ex = (u[i] >> 7) & 0xFF;
      if (ex >= 0x8A || (ex != 0 && ex <= 0x60)) hit = 1;
    }
    unsigned long long bl = __ballot(hit);
    if (t == 0) sflag = (bl != 0ULL) ? 1 : 0; // 1 = f32 inputs, 0 = bf16
  }
  __syncthreads();
  int f = sflag;
  if (b == 0 && t == 0) *flag = f;
  if (b < NB_CVT){
    int i = b*256 + t;
    #pragma unroll
    for (int s = 0; s < 11; ++s){
      int j = i - a.off[s];
      if (j >= 0 && j < a.cnt[s])
        cw[a.off[s] + j] = f ? ((const float*)a.src[s])[j]
                             : b2f(((const bf16*)a.src[s])[j]);
    }
  } else if (t < 48){                         // aet[l*16 + ty*4 + h]
    int l = t >> 4, ty = (t >> 2) & 3, h = t & 3;
    float s = 0.f;
    for (int cc = 0; cc < 16; ++cc){
      int ei = l*256 + ty*64 + h*16 + cc;
      int ai = l*64 + h*16 + cc;
      float ev = f ? ((const float*)eeraw)[ei] : b2f(((const bf16*)eeraw)[ei]);
      float av = f ? ((const float*)aeraw)[ai] : b2f(((const bf16*)aeraw)[ai]);
      s += ev*av;
    }
    aet[t] = s;
  }
}

// ---- fused mid: per-bucket CSR counting sort (250) | layer-0 proj (3125) ----
__global__ __launch_bounds__(256) void k_mid(const int* __restrict__ bcur,
        const u32* __restrict__ bins,
        int* __restrict__ cpack, int* __restrict__ rowst, int* __restrict__ cnt4,
        const int* __restrict__ xidx, const float* __restrict__ aembf,
        const float* __restrict__ Wl, const float* __restrict__ att_s,
        const float* __restrict__ att_d,
        float* __restrict__ x, u16* __restrict__ bxl,
        float* __restrict__ asrc, float* __restrict__ adst){
  __shared__ __align__(16) char smem[17408];
  int t = threadIdx.x, b = blockIdx.x;
  if (b < NBKT){
    // ---- CSR role ----
    int* c4   = (int*)smem;            // 800
    int* nst  = c4 + 800;              // 200
    int* ncur = nst + 200;             // 200
    int* bco  = ncur + 200;            // 256
    int* s    = bco + 256;             // 256
    for (int i = t; i < 800; i += 256) c4[i] = 0;
    if (t < 200) ncur[t] = 0;
    int v = 0;
    if (t < NBKT){ v = bcur[t]; if (v > CAPBKT) v = CAPBKT; }
    bco[t] = v; s[t] = v;
    __syncthreads();
    for (int o = 1; o < 256; o <<= 1){
      int a2 = s[t]; int add = (t >= o) ? s[t-o] : 0;
      __syncthreads(); s[t] = a2 + add; __syncthreads();
    }
    int gb = s[b] - bco[b];
    int tot = bco[b];
    int total = s[255];
    __syncthreads();
    for (int i = t; i < tot; i += 256){
      u32 e = bins[b*CAPBKT + i];
      atomicAdd(&c4[((e >> 18) & 0xFF)*4 + ((e >> 16) & 3)], 1);
    }
    __syncthreads();
    int deg = 0;
    if (t < 200) deg = c4[t*4] + c4[t*4+1] + c4[t*4+2] + c4[t*4+3];
    s[t] = deg; __syncthreads();
    for (int o = 1; o < 256; o <<= 1){
      int a2 = s[t]; int add = (t >= o) ? s[t-o] : 0;
      __syncthreads(); s[t] = a2 + add; __syncthreads();
    }
    if (t < 200) nst[t] = s[t] - deg;
    __syncthreads();
    if (t < 200){
      int n = b*200 + t;
      rowst[n] = gb + nst[t];
      *(int4*)&cnt4[n*4] = make_int4(c4[t*4], c4[t*4+1], c4[t*4+2], c4[t*4+3]);
    }
    if (b == 0 && t == 0) rowst[NN] = total;
    for (int i = t; i < tot; i += 256){
      u32 e = bins[b*CAPBKT + i];
      int nl = (e >> 18) & 0xFF;
      int pos = nst[nl] + atomicAdd(&ncur[nl], 1);
      cpack[gb + pos] = (int)(e & 0x3FFFF);   // src | ty<<16
    }
    return;
  }
  // ---- proj0 role ----
  float* Ws = (float*)smem;            // 4096 floats
  float* xs = Ws + 4096;               // 256 floats
  int bp = b - NBKT;
  for (int i = t; i < 4096; i += 256) Ws[i] = Wl[i];
  int c = t & 63, wv = t >> 6;
  float ats = att_s[c], atd = att_d[c];
  for (int pass = 0; pass < 4; ++pass){
    int n = bp*16 + pass*4 + wv;
    float xv = aembf[xidx[n]*64 + c];
    x[n*64 + c] = xv;
    __syncthreads();
    xs[t] = xv;
    __syncthreads();
    const float* xr = &xs[wv*64];
    float acc = 0.f;
    #pragma unroll
    for (int k = 0; k < 64; ++k) acc += xr[k]*Ws[k*64 + c];
    bxl[n*64 + c] = f2u(acc);
    float vs = acc*ats, vd = acc*atd;
    #pragma unroll
    for (int o = 8; o >= 1; o >>= 1){ vs += __shfl_xor(vs,o,64); vd += __shfl_xor(vd,o,64); }
    if ((c & 15) == 0){ asrc[n*4 + (c>>4)] = vs; adst[n*4 + (c>>4)] = vd; }
  }
}

// BN(prev)+relu+residual then project; stats reduced inline from bnpart[l]
__global__ __launch_bounds__(256) void k_bnproj(
    const float* __restrict__ opre, const float* __restrict__ bnp,
    const float* __restrict__ gam, const float* __restrict__ bet,
    const float* __restrict__ Wl,
    const float* __restrict__ att_s, const float* __restrict__ att_d,
    float* __restrict__ x, u16* __restrict__ bxl,
    float* __restrict__ asrc, float* __restrict__ adst){
  __shared__ float Ws[4096];
  __shared__ float xs[256];
  __shared__ float sred[256];
  __shared__ float stat[128];
  int t = threadIdx.x;
  // inline BN stats: sum over NPARTS partials (L2-hot broadcast)
  {
    int cc = t & 127;
    float s = 0.f;
    for (int p2 = t >> 7; p2 < NPARTS; p2 += 2) s += bnp[p2*128 + cc];
    sred[t] = s;
  }
  for (int i = t; i < 4096; i += 256) Ws[i] = Wl[i];
  __syncthreads();
  if (t < 128) stat[t] = sred[t] + sred[128 + t];
  __syncthreads();
  int c = t & 63, wv = t >> 6;
  float mu  = stat[c] * (1.f/NN);
  float var = stat[64+c] * (1.f/NN) - mu*mu;
  float rstd = rsqrtf(var + BNEPS);
  float g = gam[c], be = bet[c];
  float ats = att_s[c], atd = att_d[c];
  for (int pass = 0; pass < 4; ++pass){
    int n = blockIdx.x*16 + pass*4 + wv;
    float o = (opre[n*64 + c] - mu)*rstd*g + be;
    float xv = x[n*64 + c] + fmaxf(o, 0.f);
    x[n*64 + c] = xv;
    __syncthreads();
    xs[t] = xv;
    __syncthreads();
    const float* xr = &xs[wv*64];
    float acc = 0.f;
    #pragma unroll
    for (int k = 0; k < 64; ++k) acc += xr[k]*Ws[k*64 + c];
    bxl[n*64 + c] = f2u(acc);
    float vs = acc*ats, vd = acc*atd;
    #pragma unroll
    for (int o2 = 8; o2 >= 1; o2 >>= 1){ vs += __shfl_xor(vs,o2,64); vd += __shfl_xor(vd,o2,64); }
    if ((c & 15) == 0){ asrc[n*4 + (c>>4)] = vs; adst[n*4 + (c>>4)] = vd; }
  }
}

// ---- aggregation: 8 nodes/block, channel-pair packing (r13 best-known):
//      phase1 weights->wsh float4 + ents stash; phase2 half-wave edge pairs ----
__global__ __launch_bounds__(256) void k_aggr(
    const u16* __restrict__ bxl,
    const float* __restrict__ asrc, const float* __restrict__ adst,
    const int* __restrict__ cnt4, const int* __restrict__ rowst,
    const int* __restrict__ cpack,
    const float* __restrict__ eeg, const float* __restrict__ aetg,
    const float* __restrict__ biasg,
    float* __restrict__ opre, float* __restrict__ bnp){
  __shared__ __align__(16) float ee[256];
  __shared__ float aetL[16];
  __shared__ float adl[32];
  __shared__ float4 wsh[MAXS];
  __shared__ int ents[MAXS];
  __shared__ float redA[256], redB[256];
  __shared__ int rs[9];
  int t = threadIdx.x;
  int n0 = blockIdx.x*8;
  ee[t] = eeg[t];
  if (t < 16) aetL[t] = aetg[t];
  if (t >= 32 && t < 64) adl[t-32] = adst[n0*4 + (t-32)];
  if (t >= 64 && t < 73) rs[t-64] = rowst[n0 + (t-64)];
  __syncthreads();
  int jb0 = rs[0], cnt = rs[8] - jb0;
  int lim = cnt < MAXS ? cnt : MAXS;
  // phase 1: per-slot attention weights + cpack stash
  for (int s = t; s < lim; s += 256){
    int j = jb0 + s;
    int pk = cpack[j];
    ents[s] = pk;
    int sr = pk & 0xFFFF, ty = pk >> 16;
    int dl = (j>=rs[1])+(j>=rs[2])+(j>=rs[3])+(j>=rs[4])+(j>=rs[5])+(j>=rs[6])+(j>=rs[7]);
    float4 as4 = *(const float4*)&asrc[sr*4];
    float a0 = as4.x + adl[dl*4+0] + aetL[ty*4+0]; a0 = a0>=0.f ? a0 : NEG*a0;
    float a1 = as4.y + adl[dl*4+1] + aetL[ty*4+1]; a1 = a1>=0.f ? a1 : NEG*a1;
    float a2 = as4.z + adl[dl*4+2] + aetL[ty*4+2]; a2 = a2>=0.f ? a2 : NEG*a2;
    float a3 = as4.w + adl[dl*4+3] + aetL[ty*4+3]; a3 = a3>=0.f ? a3 : NEG*a3;
    wsh[s] = make_float4(__expf(a0), __expf(a1), __expf(a2), __expf(a3));
  }
  __syncthreads();
  // phase 2: wave wv handles nodes wv and wv+4; half-waves split edge pairs
  int wv = t >> 6, lane = t & 63;
  int ep = lane >> 5, li = lane & 31;
  int ci = li << 1, h = ci >> 4;
  const u32* bxl32 = (const u32*)bxl;
  const float* wshf = (const float*)wsh;
  float sA0 = 0.f, sA1 = 0.f, sB0 = 0.f, sB1 = 0.f;
  #pragma unroll
  for (int half = 0; half < 2; ++half){
    int node = wv + half*4;
    int n = n0 + node;
    int jb = rs[node], je = rs[node+1];
    int4 c4 = *(const int4*)&cnt4[n*4];
    int deg = c4.x + c4.y + c4.z + c4.w;
    float inv = 1.f / (float)(deg > 0 ? deg : 1);
    float2 eA = *(const float2*)&ee[ci];
    float2 eB = *(const float2*)&ee[64+ci];
    float2 eC = *(const float2*)&ee[128+ci];
    float2 eD = *(const float2*)&ee[192+ci];
    float aes = ((float)c4.x*aetL[h] + (float)c4.y*aetL[4+h]
               + (float)c4.z*aetL[8+h] + (float)c4.w*aetL[12+h]) * inv;
    float adn = adl[node*4 + h];
    float a = asrc[n*4 + h] + adn + aes;
    a = a >= 0.f ? a : NEG*a;
    float wself = __expf(a);
    float acc0 = 0.f, acc1 = 0.f, den = 0.f;
    if (ep == 0){
      float eam0 = ((float)c4.x*eA.x + (float)c4.y*eB.x + (float)c4.z*eC.x + (float)c4.w*eD.x)*inv;
      float eam1 = ((float)c4.x*eA.y + (float)c4.y*eB.y + (float)c4.z*eC.y + (float)c4.w*eD.y)*inv;
      u32 vs_ = bxl32[n*32 + li];
      den = wself;
      acc0 = wself*(__uint_as_float(vs_ << 16) + eam0);
      acc1 = wself*(__uint_as_float(vs_ & 0xFFFF0000u) + eam1);
    }
    int jlim = jb0 + lim;
    int jeP = je < jlim ? je : jlim;
    int j = jb;
    for (; j + 8 <= jeP; j += 8){
      int so = j - jb0 + ep;
      int p0 = ents[so], p1 = ents[so+2], p2 = ents[so+4], p3 = ents[so+6];
      u32 v0 = bxl32[(p0 & 0xFFFF)*32 + li];
      u32 v1 = bxl32[(p1 & 0xFFFF)*32 + li];
      u32 v2 = bxl32[(p2 & 0xFFFF)*32 + li];
      u32 v3 = bxl32[(p3 & 0xFFFF)*32 + li];
      float w0 = wshf[(so  )*4 + h], w1 = wshf[(so+2)*4 + h];
      float w2 = wshf[(so+4)*4 + h], w3 = wshf[(so+6)*4 + h];
      float2 e0 = *(const float2*)&ee[(p0 >> 16)*64 + ci];
      float2 e1 = *(const float2*)&ee[(p1 >> 16)*64 + ci];
      float2 e2 = *(const float2*)&ee[(p2 >> 16)*64 + ci];
      float2 e3 = *(const float2*)&ee[(p3 >> 16)*64 + ci];
      acc0 += w0*(__uint_as_float(v0 << 16) + e0.x);
      acc1 += w0*(__uint_as_float(v0 & 0xFFFF0000u) + e0.y); den += w0;
      acc0 += w1*(__uint_as_float(v1 << 16) + e1.x);
      acc1 += w1*(__uint_as_float(v1 & 0xFFFF0000u) + e1.y); den += w1;
      acc0 += w2*(__uint_as_float(v2 << 16) + e2.x);
      acc1 += w2*(__uint_as_float(v2 & 0xFFFF0000u) + e2.y); den += w2;
      acc0 += w3*(__uint_as_float(v3 << 16) + e3.x);
      acc1 += w3*(__uint_as_float(v3 & 0xFFFF0000u) + e3.y); den += w3;
    }
    for (; j + 2 <= jeP; j += 2){
      int so = j - jb0 + ep;
      int p = ents[so];
      u32 v = bxl32[(p & 0xFFFF)*32 + li];
      float w = wshf[so*4 + h];
      float2 e = *(const float2*)&ee[(p >> 16)*64 + ci];
      acc0 += w*(__uint_as_float(v << 16) + e.x);
      acc1 += w*(__uint_as_float(v & 0xFFFF0000u) + e.y);
      den += w;
    }
    if (j < jeP && ep == 0){          // odd leftover: half-wave 0 only
      int so = j - jb0;
      int p = ents[so];
      u32 v = bxl32[(p & 0xFFFF)*32 + li];
      float w = wshf[so*4 + h];
      float2 e = *(const float2*)&ee[(p >> 16)*64 + ci];
      acc0 += w*(__uint_as_float(v << 16) + e.x);
      acc1 += w*(__uint_as_float(v & 0xFFFF0000u) + e.y);
      den += w;
    }
    for (j = jeP; j < je; ++j){       // overflow fallback (never for this data)
      if (ep == 0){
        int pk = cpack[j];
        int s_ = pk & 0xFFFF, ty = pk >> 16;
        float aa = asrc[s_*4 + h] + adn + aetL[ty*4 + h];
        aa = aa >= 0.f ? aa : NEG*aa;
        float wj = __expf(aa);
        u32 v = bxl32[s_*32 + li];
        float2 e = *(const float2*)&ee[ty*64 + ci];
        acc0 += wj*(__uint_as_float(v << 16) + e.x);
        acc1 += wj*(__uint_as_float(v & 0xFFFF0000u) + e.y);
        den += wj;
      }
    }
    // merge half-waves
    acc0 += __shfl_xor(acc0, 32, 64);
    acc1 += __shfl_xor(acc1, 32, 64);
    den  += __shfl_xor(den, 32, 64);
    float2 bi = *(const float2*)&biasg[ci];
    float out0 = acc0/den + bi.x;
    float out1 = acc1/den + bi.y;
    if (ep == 0) *(float2*)&opre[n*64 + ci] = make_float2(out0, out1);
    sA0 += out0; sA1 += out1; sB0 += out0*out0; sB1 += out1*out1;
  }
  if (ep == 0){
    redA[wv*64 + ci] = sA0; redA[wv*64 + ci + 1] = sA1;
    redB[wv*64 + ci] = sB0; redB[wv*64 + ci + 1] = sB1;
  }
  __syncthreads();
  int part = blockIdx.x & (NPARTS-1);
  if (t < 64){
    atomicAdd(&bnp[part*128 + t], redA[t]+redA[64+t]+redA[128+t]+redA[192+t]);
  } else if (t < 128){
    int cc = t - 64;
    atomicAdd(&bnp[part*128 + 64 + cc], redB[cc]+redB[64+cc]+redB[128+cc]+redB[192+cc]);
  }
}

// ---- prediction head: BN(layer2) inline stats + residual + per-node dots ----
__global__ __launch_bounds__(256) void k_bnpred(
    const float* __restrict__ x, const float* __restrict__ opre,
    const float* __restrict__ bnp, const float* __restrict__ gam,
    const float* __restrict__ bet, const float* __restrict__ pW,
    float* __restrict__ s1, float* __restrict__ s2){
  __shared__ float sred[256];
  __shared__ float stat[128];
  int t = threadIdx.x;
  {
    int cc = t & 127;
    float s = 0.f;
    for (int p2 = t >> 7; p2 < NPARTS; p2 += 2) s += bnp[p2*128 + cc];
    sred[t] = s;
  }
  __syncthreads();
  if (t < 128) stat[t] = sred[t] + sred[128 + t];
  __syncthreads();
  int wv = t >> 6, c = t & 63;
  int n = blockIdx.x*4 + wv;
  float mu  = stat[c] * (1.f/NN);
  float var = stat[64+c] * (1.f/NN) - mu*mu;
  float o = (opre[n*64 + c] - mu)*rsqrtf(var + BNEPS)*gam[c] + bet[c];
  float xv = x[n*64 + c] + fmaxf(o, 0.f);
  float v1 = xv*pW[c], v2 = xv*pW[64 + c];
  #pragma unroll
  for (int o2 = 32; o2 >= 1; o2 >>= 1){ v1 += __shfl_xor(v1,o2,64); v2 += __shfl_xor(v2,o2,64); }
  if (c == 0){ s1[n] = v1; s2[n] = v2; }
}

__global__ void k_pred_edge(const int* __restrict__ src, const int* __restrict__ dst,
        const float* __restrict__ s1, const float* __restrict__ s2,
        const float* __restrict__ pbf, const int* __restrict__ flag, void* out){
  int e = blockIdx.x*256 + threadIdx.x;
  if (e < NE){
    float v = s1[src[e]] + s2[dst[e]] + pbf[0];
    if (*flag) ((float*)out)[e] = v;
    else       ((bf16*)out)[e] = __float2bfloat16(v);
  }
}

// ---- launch ----
extern "C" void kernel_launch(void* const* d_in, const int* in_sizes, int n_in,
                              void* d_out, int out_size, void* d_ws, size_t ws_size,
                              hipStream_t stream){
  const int*  xidx = (const int*)d_in[0];
  const int*  eidx = (const int*)d_in[1];
  const int*  ety  = (const int*)d_in[2];
  const int* srcp = eidx, *dstp = eidx + NE;

  // 256B-aligned bump allocator
  char* base = (char*)d_ws;
  auto alloc = [&](size_t bytes) -> char* {
    char* r = base; base += (bytes + 255) & ~(size_t)255; return r;
  };
  float* x      = (float*)alloc(NN*64*4);
  float* opre   = (float*)alloc(NN*64*4);
  float* asrc   = (float*)alloc(NN*4*4);
  float* adst   = (float*)alloc(NN*4*4);
  float* s1     = (float*)alloc(NN*4);
  float* s2     = (float*)alloc(NN*4);
  float* cw     = (float*)alloc(15392*4);
  float* aet    = (float*)alloc(64*4);
  char*  zchunk = alloc(3*NPARTS*128*4 + 256*4);  // bnpart[3] + bcur
  float* bnpart = (float*)zchunk;
  int*   bcur   = (int*)(zchunk + 3*NPARTS*128*4);
  size_t zbytes = 3*NPARTS*128*4 + 256*4;
  u32*   bins   = (u32*)alloc((size_t)NBKT*CAPBKT*4);
  int*   cpack  = (int*)alloc(NE*4);
  int*   rowst  = (int*)alloc((NN+4)*4);
  int*   cnt4   = (int*)alloc(NN*4*4);
  int*   flag   = (int*)alloc(256);
  u16*   bxl    = (u16*)alloc(NN*64*2);

  const int O_AEMB = 0,     N_AEMB = 1024;
  const int O_W    = 1024,  N_W    = 12288;
  const int O_AS   = 13312, N_AS   = 192;
  const int O_AD   = 13504, N_AD   = 192;
  const int O_AE   = 13696, N_AE   = 192;
  const int O_BI   = 13888, N_BI   = 192;
  const int O_EE   = 14080, N_EE   = 768;
  const int O_GA   = 14848, N_GA   = 192;
  const int O_BE   = 15040, N_BE   = 192;
  const int O_PW   = 15232, N_PW   = 128;
  const int O_PB   = 15360, N_PB   = 1;

  CvtArgs ca;
  ca.src[0]=d_in[3];  ca.off[0]=O_AEMB; ca.cnt[0]=N_AEMB;
  ca.src[1]=d_in[4];  ca.off[1]=O_W;    ca.cnt[1]=N_W;
  ca.src[2]=d_in[5];  ca.off[2]=O_AS;   ca.cnt[2]=N_AS;
  ca.src[3]=d_in[6];  ca.off[3]=O_AD;   ca.cnt[3]=N_AD;
  ca.src[4]=d_in[7];  ca.off[4]=O_AE;   ca.cnt[4]=N_AE;
  ca.src[5]=d_in[8];  ca.off[5]=O_BI;   ca.cnt[5]=N_BI;
  ca.src[6]=d_in[9];  ca.off[6]=O_EE;   ca.cnt[6]=N_EE;
  ca.src[7]=d_in[10]; ca.off[7]=O_GA;   ca.cnt[7]=N_GA;
  ca.src[8]=d_in[11]; ca.off[8]=O_BE;   ca.cnt[8]=N_BE;
  ca.src[9]=d_in[12]; ca.off[9]=O_PW;   ca.cnt[9]=N_PW;
  ca.src[10]=d_in[13];ca.off[10]=O_PB;  ca.cnt[10]=N_PB;

  hipMemsetAsync(zchunk, 0, zbytes, stream);
  k_front<<<NB_FRONT, 256, 0, stream>>>(ca, d_in[9], d_in[7], srcp, dstp, ety,
                                        cw, aet, flag, bcur, bins);
  k_mid<<<NB_MID, 256, 0, stream>>>(bcur, bins, cpack, rowst, cnt4,
                                    xidx, cw + O_AEMB, cw + O_W,
                                    cw + O_AS, cw + O_AD, x, bxl, asrc, adst);
  for (int l = 0; l < 3; ++l){
    k_aggr<<<NN/8, 256, 0, stream>>>(bxl, asrc, adst, cnt4, rowst, cpack,
                                     cw + O_EE + l*256, aet + l*16,
                                     cw + O_BI + l*64, opre, bnpart + l*NPARTS*128);
    if (l < 2)
      k_bnproj<<<NN/16, 256, 0, stream>>>(opre, bnpart + l*NPARTS*128,
                                          cw + O_GA + l*64, cw + O_BE + l*64,
                                          cw + O_W + (l+1)*4096,
                                          cw + O_AS + (l+1)*64, cw + O_AD + (l+1)*64,
                                          x, bxl, asrc, adst);
  }
  k_bnpred<<<NN/4, 256, 0, stream>>>(x, opre, bnpart + 2*NPARTS*128,
                                     cw + O_GA + 128, cw + O_BE + 128,
                                     cw + O_PW, s1, s2);
  k_pred_edge<<<NB_EDGE, 256, 0, stream>>>(srcp, dstp, s1, s2, cw + O_PB, flag, d_out);
}